// Round 2
// baseline (99.167 us; speedup 1.0000x reference)
//
#include <hip/hip_runtime.h>

// Bit-exact replica of XLA:CPU's vectorized f32 exp AS COMPILED with
// fast-math contraction (== Eigen classic pexp_float with pmadd=FMA on AVX2):
//   m = floor(fma(x, LOG2EF, 0.5))
//   r = fma(m, -C1, x); r = fma(m, C2, r)      (Cody-Waite, FMA form)
//   Horner p0..p5 with FMA; y = fma(y, r^2, r); y = y + 1
//   result = max(y * 2^m, x_original)
// Non-FMA ops must stay un-contracted -> pragma contract(off) + explicit fmaf.
__device__ __forceinline__ float xla_expf(float xin) {
#pragma clang fp contract(off)
  float xc = fminf(xin, 88.3762626647950f);
  xc = fmaxf(xc, -88.3762626647949f);
  float m = floorf(fmaf(xc, 1.44269504088896341f, 0.5f));
  float r = fmaf(m, -0.693359375f, xc);
  r = fmaf(m, 2.12194440e-4f, r);
  float r2 = r * r;
  float y = 1.9875691500E-4f;            // p0
  y = fmaf(y, r, 1.3981999507E-3f);      // p1
  y = fmaf(y, r, 8.3334519073E-3f);      // p2
  y = fmaf(y, r, 4.1665795894E-2f);      // p3
  y = fmaf(y, r, 1.6666665459E-1f);      // p4
  y = fmaf(y, r, 5.0000001201E-1f);      // p5
  y = fmaf(y, r2, r);
  y = y + 1.0f;
  int n = (int)m;
  float twon = __int_as_float((n + 127) << 23);
  float res = y * twon;
  return fmaxf(res, xin);                // Eigen/XLA final pmax vs UNCLAMPED input
}

// logistic(x) = 1 / (1 + exp(-x)) — XLA LogisticExpander form.
// add and divide are plain IEEE ops (divide correctly rounded on both sides).
__device__ __forceinline__ float xla_sigmoid(float f) {
#pragma clang fp contract(off)
  float e = xla_expf(-f);
  float denom = 1.0f + e;
  return 1.0f / denom;
}

// Layout: value v occupies floats [v*32, v*32+32), MSB first.
// Lane handles float4 at index i -> value v = i>>3, nibble k = i&7,
// bit positions (shifts) 31-4k .. 28-4k. 8 lanes OR-reduce via shfl_xor.
__global__ void __launch_bounds__(256) spike_sigmoid_kernel(
    const float4* __restrict__ in4, float4* __restrict__ out4, int n4) {
  int tid = blockIdx.x * blockDim.x + threadIdx.x;
  int stride = gridDim.x * blockDim.x;
  for (int i = tid; i < n4; i += stride) {
    float4 v = in4[i];
    int sh = 28 - 4 * (i & 7);   // shift of this nibble's LSB
    unsigned nib = (v.x > 0.5f ? 8u : 0u) | (v.y > 0.5f ? 4u : 0u) |
                   (v.z > 0.5f ? 2u : 0u) | (v.w > 0.5f ? 1u : 0u);
    unsigned u = nib << sh;
    // OR-reduce across the 8 lanes sharing this value (i>>3 invariant
    // under xor masks 1,2,4 because tiles are wave-aligned).
    u |= __shfl_xor(u, 1);
    u |= __shfl_xor(u, 2);
    u |= __shfl_xor(u, 4);
    float f = __uint_as_float(u);
    float s = xla_sigmoid(f);
    unsigned sb = __float_as_uint(s);
    float4 o;
    o.x = (float)((sb >> (sh + 3)) & 1u);
    o.y = (float)((sb >> (sh + 2)) & 1u);
    o.z = (float)((sb >> (sh + 1)) & 1u);
    o.w = (float)((sb >> sh) & 1u);
    out4[i] = o;
  }
}

extern "C" void kernel_launch(void* const* d_in, const int* in_sizes, int n_in,
                              void* d_out, int out_size, void* d_ws, size_t ws_size,
                              hipStream_t stream) {
  const float4* in4 = (const float4*)d_in[0];
  float4* out4 = (float4*)d_out;
  int n4 = in_sizes[0] / 4;  // 16,000,000 float4s (multiple of 8 per value)
  dim3 block(256);
  dim3 grid(2048);
  spike_sigmoid_kernel<<<grid, block, 0, stream>>>(in4, out4, n4);
}